// Round 7
// baseline (276.199 us; speedup 1.0000x reference)
//
#include <hip/hip_runtime.h>
#include <hip/hip_bf16.h>

#define B_ 4
#define T_ 4096
#define S_ 1024
#define HID_ 1024
#define CTX_ 768
#define EMB_ 1024
#define H_ 16
#define D_ 64

// Q pre-scale: (1/sqrt(D)) * log2(e) so softmax runs in exp2 domain.
#define QSCALE 0.18033688011112042f

typedef __attribute__((ext_vector_type(8))) short short8;
typedef __attribute__((ext_vector_type(4))) float f32x4;
typedef __attribute__((ext_vector_type(4))) unsigned short us4;
typedef unsigned short ushort_t;

__device__ inline ushort_t f2b(float f) {
  union { float f; unsigned u; } x; x.f = f;
  return (ushort_t)((x.u + 0x7fffu + ((x.u >> 16) & 1u)) >> 16);
}
// compiler-recognized packed f32->bf16 (v_cvt_pk_bf16_f32)
__device__ inline unsigned cvtpk2(float a, float b) {
  __hip_bfloat162 h = __float22bfloat162_rn(float2{a, b});
  union { __hip_bfloat162 h; unsigned u; } c; c.h = h; return c.u;
}
__device__ inline ushort_t f2b_fast(float f) {
  __hip_bfloat16 h = __float2bfloat16(f);
  union { __hip_bfloat16 h; ushort_t u; } c; c.h = h; return c.u;
}

using gu32p = const __attribute__((address_space(1))) unsigned int*;
using lu32p = __attribute__((address_space(3))) unsigned int*;
__device__ inline void gload16(const ushort_t* g, ushort_t* l) {
  __builtin_amdgcn_global_load_lds((gu32p)(const void*)g, (lu32p)(void*)l, 16, 0, 0);
}

// ---- flat f32 -> bf16 convert, 8 elems/thread ----
__global__ __launch_bounds__(256) void conv_bf16(const float* __restrict__ in,
                                                 ushort_t* __restrict__ out) {
  const size_t i = ((size_t)blockIdx.x * 256 + threadIdx.x) * 8;
  const float4 a = *(const float4*)(in + i);
  const float4 b = *(const float4*)(in + i + 4);
  uint4 u;
  u.x = cvtpk2(a.x, a.y); u.y = cvtpk2(a.z, a.w);
  u.z = cvtpk2(b.x, b.y); u.w = cvtpk2(b.z, b.w);
  *(uint4*)(out + i) = u;
}

// ---- W[K][N] f32 -> Wt[N][K] bf16 (transpose+convert), 32x32 tiles ----
__global__ __launch_bounds__(256) void convT(const float* __restrict__ W,
                                             ushort_t* __restrict__ Wt,
                                             int K, int N) {
  __shared__ float Ls[32][33];
  const int tid = threadIdx.x;
  const int n0 = blockIdx.x * 32, k0 = blockIdx.y * 32;
  const int r = tid >> 3, c4 = (tid & 7) * 4;
  const float4 v = *(const float4*)&W[(size_t)(k0 + r) * N + n0 + c4];
  Ls[r][c4] = v.x; Ls[r][c4 + 1] = v.y; Ls[r][c4 + 2] = v.z; Ls[r][c4 + 3] = v.w;
  __syncthreads();
  us4 o;
  o.x = f2b_fast(Ls[c4][r]);     o.y = f2b_fast(Ls[c4 + 1][r]);
  o.z = f2b_fast(Ls[c4 + 2][r]); o.w = f2b_fast(Ls[c4 + 3][r]);
  *(us4*)&Wt[(size_t)(n0 + r) * K + k0 + c4] = o;
}

// ---- m97-style GEMM (128x128): used for K-proj / V-proj (small M) ----
// EPI: 0 = bf16 out, 2 = V^T bf16 out [b][h][d][s]
template<int EPI>
__global__ __launch_bounds__(256) void gemm128(
    const ushort_t* __restrict__ A, const ushort_t* __restrict__ Bt,
    void* __restrict__ Cp, const float* __restrict__ bias,
    int M, int Kd, int N)
{
  __shared__ ushort_t As[128 * 32];
  __shared__ ushort_t Bs[128 * 32];
  const int tid = threadIdx.x;
  const int bn = blockIdx.x, bm = blockIdx.y;
  const int lane = tid & 63, w = tid >> 6;
  const int lr = lane & 15, lg = lane >> 4;
  const int wr = w >> 1, wc = w & 1;

  f32x4 acc[4][4] = {};

  const int srow = tid >> 2, scol = (tid & 3) * 8;
  const ushort_t* ga = A + (size_t)(bm * 128 + srow) * Kd + scol;
  const ushort_t* gb = Bt + (size_t)(bn * 128 + srow) * Kd + scol;
  ushort_t* la = &As[tid * 8];
  ushort_t* lb = &Bs[tid * 8];
  const size_t rstep = (size_t)64 * Kd;

  for (int k0 = 0; k0 < Kd; k0 += 32) {
    gload16(ga + k0, la);
    gload16(ga + k0 + rstep, la + 2048);
    gload16(gb + k0, lb);
    gload16(gb + k0 + rstep, lb + 2048);
    __syncthreads();
    short8 af[4], bf[4];
#pragma unroll
    for (int m = 0; m < 4; ++m)
      af[m] = *(const short8*)&As[(wr * 64 + m * 16 + lr) * 32 + lg * 8];
#pragma unroll
    for (int n = 0; n < 4; ++n)
      bf[n] = *(const short8*)&Bs[(wc * 64 + n * 16 + lr) * 32 + lg * 8];
#pragma unroll
    for (int m = 0; m < 4; ++m)
#pragma unroll
      for (int n = 0; n < 4; ++n)
        acc[m][n] = __builtin_amdgcn_mfma_f32_16x16x32_bf16(af[m], bf[n], acc[m][n], 0, 0, 0);
    __syncthreads();
  }

  const int row0 = bm * 128 + wr * 64 + lg * 4;  // + m*16 + i
  const int col0 = bn * 128 + wc * 64 + lr;      // + n*16

  if constexpr (EPI == 2) {
    ushort_t* C = (ushort_t*)Cp;
#pragma unroll
    for (int m = 0; m < 4; ++m) {
      const int rbase = row0 + m * 16;
      const int bb = rbase >> 10;         // S_ = 1024 rows per batch
      const int s0 = rbase & (S_ - 1);
#pragma unroll
      for (int n = 0; n < 4; ++n) {
        const int col = col0 + n * 16;
        const int hh = col >> 6, dd = col & 63;
        us4 o;
        o.x = f2b(acc[m][n][0]); o.y = f2b(acc[m][n][1]);
        o.z = f2b(acc[m][n][2]); o.w = f2b(acc[m][n][3]);
        *(us4*)&C[(((size_t)bb * H_ + hh) * D_ + dd) * S_ + s0] = o;
      }
    }
  } else {
    ushort_t* C = (ushort_t*)Cp;
#pragma unroll
    for (int m = 0; m < 4; ++m)
#pragma unroll
      for (int n = 0; n < 4; ++n) {
        const int col = col0 + n * 16;
#pragma unroll
        for (int i = 0; i < 4; ++i)
          C[(size_t)(row0 + m * 16 + i) * N + col] = f2b(acc[m][n][i]);
      }
  }
}

// ---- gemm256: 256x256 tile, 8 waves (2Mx4N), counted-vmcnt 4-slot ring ----
// EPI: 1 = bf16 out * QSCALE, 3 = f32 + bias
template<int EPI>
__global__ __launch_bounds__(512) void gemm256(
    const ushort_t* __restrict__ A, const ushort_t* __restrict__ Bt,
    void* __restrict__ Cp, const float* __restrict__ bias,
    int M, int Kd, int N)
{
  extern __shared__ ushort_t L[];   // 4 slots x (A 8192 + B 8192 ushorts)
  const int tid = threadIdx.x;
  const int lane = tid & 63, wid = tid >> 6;
  const int lr = lane & 15, lg = lane >> 4;
  const int wm = wid >> 2, wn = wid & 3;

  // bijective XCD swizzle (gridDim.x % 8 == 0)
  const int cpx = (int)gridDim.x >> 3;
  const int lin = (int)blockIdx.x;
  const int swz = (lin & 7) * cpx + (lin >> 3);
  const int nbn = N >> 8;
  const int bm = swz / nbn, bn = swz % nbn;

  // staging: thread t -> dest chunk (t&3), dest rows (t>>2) and (t>>2)+128
  const int sr = tid >> 2;
  const int csrc = (tid & 3) ^ ((sr >> 1) & 3);
  const ushort_t* gA = A + (size_t)(bm * 256 + sr) * Kd + csrc * 8;
  const ushort_t* gB = Bt + (size_t)(bn * 256 + sr) * Kd + csrc * 8;
  const size_t half = (size_t)128 * Kd;
  ushort_t* const dA = L + tid * 8;
  ushort_t* const dB = L + 8192 + tid * 8;

  f32x4 acc[8][4] = {};
  const int NT = Kd >> 5;

#define STAGE256(c) do {                                \
    const int slot_ = ((c) & 3) * 16384;                \
    const int k0_ = (c) << 5;                           \
    gload16(gA + k0_, dA + slot_);                      \
    gload16(gA + k0_ + half, dA + slot_ + 4096);        \
    gload16(gB + k0_, dB + slot_);                      \
    gload16(gB + k0_ + half, dB + slot_ + 4096);        \
  } while (0)

  STAGE256(0); STAGE256(1); STAGE256(2);
  asm volatile("s_waitcnt vmcnt(8)" ::: "memory");   // chunk 0 landed
  __builtin_amdgcn_s_barrier();
  __builtin_amdgcn_sched_barrier(0);

  for (int t = 0; t < NT; ++t) {
    if (t + 3 < NT) STAGE256(t + 3);
    const ushort_t* As_ = L + (t & 3) * 16384;
    const ushort_t* Bs_ = As_ + 8192;
    short8 af[8], bf[4];
#pragma unroll
    for (int m = 0; m < 8; ++m) {
      const int row = wm * 128 + m * 16 + lr;
      af[m] = *(const short8*)&As_[row * 32 + (lg ^ ((row >> 1) & 3)) * 8];
    }
#pragma unroll
    for (int n = 0; n < 4; ++n) {
      const int row = wn * 64 + n * 16 + lr;
      bf[n] = *(const short8*)&Bs_[row * 32 + (lg ^ ((row >> 1) & 3)) * 8];
    }
    __builtin_amdgcn_s_setprio(1);
#pragma unroll
    for (int m = 0; m < 8; ++m)
#pragma unroll
      for (int n = 0; n < 4; ++n)
        acc[m][n] = __builtin_amdgcn_mfma_f32_16x16x32_bf16(af[m], bf[n], acc[m][n], 0, 0, 0);
    __builtin_amdgcn_s_setprio(0);
    asm volatile("s_waitcnt vmcnt(8)" ::: "memory"); // chunk t+1 landed
    __builtin_amdgcn_s_barrier();                    // slot t&3 reads done (all waves)
    __builtin_amdgcn_sched_barrier(0);
  }
#undef STAGE256

  const int row0 = bm * 256 + wm * 128 + lg * 4;   // + m*16 + i
  const int col0 = bn * 256 + wn * 64 + lr;        // + n*16

  if constexpr (EPI == 3) {
    float* C = (float*)Cp;
#pragma unroll
    for (int n = 0; n < 4; ++n) {
      const int col = col0 + n * 16;
      const float bv = bias[col];
#pragma unroll
      for (int m = 0; m < 8; ++m)
#pragma unroll
        for (int i = 0; i < 4; ++i)
          C[(size_t)(row0 + m * 16 + i) * N + col] = acc[m][n][i] + bv;
    }
  } else {
    ushort_t* C = (ushort_t*)Cp;
#pragma unroll
    for (int m = 0; m < 8; ++m)
#pragma unroll
      for (int n = 0; n < 4; ++n) {
        const int col = col0 + n * 16;
#pragma unroll
        for (int i = 0; i < 4; ++i)
          C[(size_t)(row0 + m * 16 + i) * N + col] = f2b(acc[m][n][i] * QSCALE);
      }
  }
}

// ---- flash attention v6: QBLK=512 (8 waves x 64 rows = 4 qs), SBLK=64,
//      ring-3 K/V with counted vmcnt(2), swapped QK^T, no-max exp2 softmax,
//      l via ones-MFMA, same-(b,h)->same-XCD block swizzle ----
// Q bf16 [B,T,EMB] (pre-scaled by QSCALE), K bf16 [B,S,EMB], Vt bf16 [B,H,D,S].
__global__ __launch_bounds__(512) void attn_v6(
    const ushort_t* __restrict__ Q, const ushort_t* __restrict__ K,
    const ushort_t* __restrict__ Vt, ushort_t* __restrict__ C)
{
  __shared__ ushort_t Ks[3][4096];     // 3 x 64x64 bf16 (8KB each)
  __shared__ ushort_t Vs[3][4096];
  __shared__ ushort_t Ps[8][4][16][72];  // per (wave, qs); wave-private
  const int tid = threadIdx.x;
  const int lane = tid & 63, w = tid >> 6;
  const int lr = lane & 15, lg = lane >> 4;

  // block swizzle: 1D grid 512 = 8 t-chunks x 64 (b,h); all 8 t-chunks of one
  // (b,h) share i%8 (same XCD under round-robin) -> K/V stays in one L2.
  const int bid = (int)blockIdx.x;
  const int m8 = (bid >> 3) & 7;                   // t-chunk
  const int g = (bid & 7) | ((bid >> 6) << 3);     // (b,h) group 0..63
  const int h = g & 15, b = g >> 4;
  const int t0 = m8 * 512;

  // Q as B-fragments: lane holds Q[t=col=lr][d=8*lg+j], 4 q-subtiles
  short8 qf[4][2];
#pragma unroll
  for (int qs = 0; qs < 4; ++qs) {
    const size_t qrow = (size_t)b * T_ + t0 + w * 64 + qs * 16 + lr;
    const ushort_t* qp = Q + qrow * EMB_ + h * 64;
    qf[qs][0] = *(const short8*)(qp + lg * 8);
    qf[qs][1] = *(const short8*)(qp + 32 + lg * 8);
  }

  short8 ones;
#pragma unroll
  for (int j = 0; j < 8; ++j) ones[j] = (short)0x3F80;

  f32x4 o[4][4] = {};
  f32x4 lacc[4] = {};

  // unified loop-invariant LDS fragment offsets (swizzle XOR = lr&7):
  // row = c*16+lr, chunk = (h*4+lg) -> elem offset
  int offs[4][2];
#pragma unroll
  for (int c = 0; c < 4; ++c)
#pragma unroll
    for (int hh = 0; hh < 2; ++hh)
      offs[c][hh] = (c * 16 + lr) * 64 + (((hh * 4 + lg) ^ (lr & 7)) * 8);

  // staging: LDS linear dest, pre-swizzled global source (chunk ^= row&7)
  const int srow = tid >> 3, schunk = tid & 7;
  const int sswz = schunk ^ (srow & 7);
  const ushort_t* kg = K + ((size_t)b * S_ + srow) * EMB_ + h * 64 + sswz * 8;
  const ushort_t* vg = Vt + (((size_t)b * H_ + h) * D_ + srow) * S_ + sswz * 8;
  ushort_t* const ksd = &Ks[0][0];
  ushort_t* const vsd = &Vs[0][0];

  // tile compute body (slot = ring slot holding tile data)
  auto tile_body = [&](int slot) {
    const ushort_t* Kb = &Ks[slot][0];
    const ushort_t* Vb = &Vs[slot][0];
    short8 ka[4][2];
#pragma unroll
    for (int c = 0; c < 4; ++c) {
      ka[c][0] = *(const short8*)&Kb[offs[c][0]];
      ka[c][1] = *(const short8*)&Kb[offs[c][1]];
    }
#pragma unroll
    for (int qs = 0; qs < 4; ++qs) {
      f32x4 sacc[4] = {};
      __builtin_amdgcn_s_setprio(1);
#pragma unroll
      for (int c = 0; c < 4; ++c) {
        sacc[c] = __builtin_amdgcn_mfma_f32_16x16x32_bf16(ka[c][0], qf[qs][0], sacc[c], 0, 0, 0);
        sacc[c] = __builtin_amdgcn_mfma_f32_16x16x32_bf16(ka[c][1], qf[qs][1], sacc[c], 0, 0, 0);
      }
      __builtin_amdgcn_s_setprio(0);
      // no-max softmax: P = exp2(S); P^T[s=c*16+4lg+i][t=lr] -> Ps
#pragma unroll
      for (int c = 0; c < 4; ++c) {
        uint2 pk;
        pk.x = cvtpk2(exp2f(sacc[c][0]), exp2f(sacc[c][1]));
        pk.y = cvtpk2(exp2f(sacc[c][2]), exp2f(sacc[c][3]));
        *(uint2*)&Ps[w][qs][lr][c * 16 + lg * 4] = pk;
      }
    }
    // PV, sh-outer: vb shared across 4 qs; l via ones-MFMA
#pragma unroll
    for (int sh = 0; sh < 2; ++sh) {
      short8 vb[4];
#pragma unroll
      for (int dc = 0; dc < 4; ++dc)
        vb[dc] = *(const short8*)&Vb[offs[dc][sh]];
      __builtin_amdgcn_s_setprio(1);
#pragma unroll
      for (int qs = 0; qs < 4; ++qs) {
        const short8 pa = *(const short8*)&Ps[w][qs][lr][sh * 32 + lg * 8];
#pragma unroll
        for (int dc = 0; dc < 4; ++dc)
          o[qs][dc] = __builtin_amdgcn_mfma_f32_16x16x32_bf16(pa, vb[dc], o[qs][dc], 0, 0, 0);
        lacc[qs] = __builtin_amdgcn_mfma_f32_16x16x32_bf16(pa, ones, lacc[qs], 0, 0, 0);
      }
      __builtin_amdgcn_s_setprio(0);
    }
  };

  // prologue: stage tiles 0,1 into slots 0,1
  gload16(kg, ksd + tid * 8);
  gload16(vg, vsd + tid * 8);
  gload16(kg + (size_t)64 * EMB_, ksd + 4096 + tid * 8);
  gload16(vg + 64, vsd + 4096 + tid * 8);

  int slc = 0, sls = 2;   // compute slot (t%3), stage slot ((t+2)%3)
  for (int t = 0; t < 14; ++t) {
    asm volatile("s_waitcnt vmcnt(2)" ::: "memory");  // tile t landed (t+1 in flight)
    __builtin_amdgcn_s_barrier();
    __builtin_amdgcn_sched_barrier(0);
    gload16(kg + (size_t)(t + 2) * 64 * EMB_, ksd + sls * 4096 + tid * 8);
    gload16(vg + (t + 2) * 64, vsd + sls * 4096 + tid * 8);
    tile_body(slc);
    slc = (slc == 2) ? 0 : slc + 1;
    sls = (sls == 2) ? 0 : sls + 1;
  }
  // epilogue tiles 14, 15: drain 2 -> 0
  asm volatile("s_waitcnt vmcnt(2)" ::: "memory");
  __builtin_amdgcn_s_barrier();
  __builtin_amdgcn_sched_barrier(0);
  tile_body(slc);
  slc = (slc == 2) ? 0 : slc + 1;
  asm volatile("s_waitcnt vmcnt(0)" ::: "memory");
  __builtin_amdgcn_s_barrier();
  __builtin_amdgcn_sched_barrier(0);
  tile_body(slc);

  // epilogue: divide by l (accumulator-row layout), write ctx bf16 [B,T,EMB]
#pragma unroll
  for (int qs = 0; qs < 4; ++qs) {
#pragma unroll
    for (int i = 0; i < 4; ++i) {
      const float li = 1.0f / lacc[qs][i];
      const size_t trow = (size_t)b * T_ + t0 + w * 64 + qs * 16 + lg * 4 + i;
#pragma unroll
      for (int dc = 0; dc < 4; ++dc)
        C[trow * EMB_ + h * 64 + dc * 16 + lr] = f2b_fast(o[qs][dc][i] * li);
    }
  }
}

extern "C" void kernel_launch(void* const* d_in, const int* in_sizes, int n_in,
                              void* d_out, int out_size, void* d_ws, size_t ws_size,
                              hipStream_t stream) {
  const float* tokens  = (const float*)d_in[0];
  const float* context = (const float*)d_in[1];
  const float* Wq = (const float*)d_in[2];
  const float* Wk = (const float*)d_in[3];
  const float* Wv = (const float*)d_in[4];
  const float* Wo = (const float*)d_in[5];
  const float* bo = (const float*)d_in[6];
  float* out = (float*)d_out;

  // d_out doubles as scratch until the final O-proj overwrites it:
  ushort_t* Qb  = (ushort_t*)d_out;                      // 16.78M elems
  ushort_t* Tok = Qb + (size_t)B_ * T_ * EMB_;           // 16.78M elems (fills d_out exactly)
  // ws: Kb | Vtb | Cb (ctx_bf16 aliased at Cb base) | Wbuf  = 50 MB
  ushort_t* Kb   = (ushort_t*)d_ws;
  ushort_t* Vtb  = Kb + (size_t)B_ * S_ * EMB_;
  ushort_t* Cb   = Vtb + (size_t)B_ * S_ * EMB_;
  ushort_t* Wbuf = Cb + (size_t)B_ * T_ * EMB_;

  // tokens -> bf16 (in d_out upper half)
  conv_bf16<<<(B_ * T_ * HID_) / 2048, 256, 0, stream>>>(tokens, Tok);
  // Q-proj (QSCALE folded into epilogue), 256^2 counted-vmcnt kernel
  convT<<<dim3(EMB_ / 32, HID_ / 32), 256, 0, stream>>>(Wq, Wbuf, HID_, EMB_);
  gemm256<1><<<dim3((B_ * T_ / 256) * (EMB_ / 256)), 512, 131072, stream>>>(
      Tok, Wbuf, Qb, nullptr, B_ * T_, HID_, EMB_);
  // context -> bf16 (at Cb base; consumed before attn overwrites Cb)
  conv_bf16<<<(B_ * S_ * CTX_) / 2048, 256, 0, stream>>>(context, Cb);
  // K-proj
  convT<<<dim3(EMB_ / 32, CTX_ / 32), 256, 0, stream>>>(Wk, Wbuf, CTX_, EMB_);
  gemm128<0><<<dim3(EMB_ / 128, (B_ * S_) / 128), 256, 0, stream>>>(
      Cb, Wbuf, Kb, nullptr, B_ * S_, CTX_, EMB_);
  // V-proj, epilogue writes V^T [B,H,D,S]
  convT<<<dim3(EMB_ / 32, CTX_ / 32), 256, 0, stream>>>(Wv, Wbuf, CTX_, EMB_);
  gemm128<2><<<dim3(EMB_ / 128, (B_ * S_) / 128), 256, 0, stream>>>(
      Cb, Wbuf, Vtb, nullptr, B_ * S_, CTX_, EMB_);
  // attention -> ctx bf16 (overwrites Cb region)
  attn_v6<<<dim3((T_ / 512) * H_ * B_), 512, 0, stream>>>(Qb, Kb, Vtb, Cb);
  // O-proj + bias -> f32 out (overwrites Qb/Tok scratch in d_out)
  convT<<<dim3(HID_ / 32, EMB_ / 32), 256, 0, stream>>>(Wo, Wbuf, EMB_, HID_);
  gemm256<3><<<dim3((B_ * T_ / 256) * (HID_ / 256)), 512, 131072, stream>>>(
      Cb, Wbuf, out, bo, B_ * T_, EMB_, HID_);
}

// Round 8
// 229.491 us; speedup vs baseline: 1.2035x; 1.2035x over previous
//
#include <hip/hip_runtime.h>
#include <hip/hip_bf16.h>

#define B_ 4
#define T_ 4096
#define S_ 1024
#define HID_ 1024
#define CTX_ 768
#define EMB_ 1024
#define H_ 16
#define D_ 64

// Q pre-scale: (1/sqrt(D)) * log2(e) so softmax runs in exp2 domain.
#define QSCALE 0.18033688011112042f

typedef __attribute__((ext_vector_type(8))) short short8;
typedef __attribute__((ext_vector_type(4))) float f32x4;
typedef __attribute__((ext_vector_type(4))) unsigned short us4;
typedef unsigned short ushort_t;

__device__ inline ushort_t f2b(float f) {
  union { float f; unsigned u; } x; x.f = f;
  return (ushort_t)((x.u + 0x7fffu + ((x.u >> 16) & 1u)) >> 16);
}
__device__ inline unsigned cvtpk2(float a, float b) {
  __hip_bfloat162 h = __float22bfloat162_rn(float2{a, b});
  union { __hip_bfloat162 h; unsigned u; } c; c.h = h; return c.u;
}
__device__ inline ushort_t f2b_fast(float f) {
  __hip_bfloat16 h = __float2bfloat16(f);
  union { __hip_bfloat16 h; ushort_t u; } c; c.h = h; return c.u;
}

using gu32p = const __attribute__((address_space(1))) unsigned int*;
using lu32p = __attribute__((address_space(3))) unsigned int*;
__device__ inline void gload16(const ushort_t* g, ushort_t* l) {
  __builtin_amdgcn_global_load_lds((gu32p)(const void*)g, (lu32p)(void*)l, 16, 0, 0);
}

// ---- prep: fused f32->bf16 convs + weight transposes (branch by block range) ----
__device__ inline void conv_body(const float* __restrict__ in, ushort_t* __restrict__ out,
                                 int blk, int tid) {
  const size_t i = ((size_t)blk * 256 + tid) * 8;
  const float4 a = *(const float4*)(in + i);
  const float4 b = *(const float4*)(in + i + 4);
  uint4 u;
  u.x = cvtpk2(a.x, a.y); u.y = cvtpk2(a.z, a.w);
  u.z = cvtpk2(b.x, b.y); u.w = cvtpk2(b.z, b.w);
  *(uint4*)(out + i) = u;
}

// W[K][1024] f32 -> Wt[1024][K] bf16, 32x32 tile #tile
__device__ inline void convT_body(const float* __restrict__ W, ushort_t* __restrict__ Wt,
                                  int K, int tile, int tid, float (*Ls)[33]) {
  const int n0 = (tile & 31) * 32, k0 = (tile >> 5) * 32;
  const int r = tid >> 3, c4 = (tid & 7) * 4;
  const float4 v = *(const float4*)&W[(size_t)(k0 + r) * 1024 + n0 + c4];
  Ls[r][c4] = v.x; Ls[r][c4 + 1] = v.y; Ls[r][c4 + 2] = v.z; Ls[r][c4 + 3] = v.w;
  __syncthreads();
  us4 o;
  o.x = f2b_fast(Ls[c4][r]);     o.y = f2b_fast(Ls[c4 + 1][r]);
  o.z = f2b_fast(Ls[c4 + 2][r]); o.w = f2b_fast(Ls[c4 + 3][r]);
  *(us4*)&Wt[(size_t)(n0 + r) * K + k0 + c4] = o;
}

__global__ __launch_bounds__(256) void prepA(
    const float* __restrict__ tokens, const float* __restrict__ context,
    const float* __restrict__ Wq, const float* __restrict__ Wk,
    const float* __restrict__ Wv,
    ushort_t* __restrict__ Tok, ushort_t* __restrict__ CtxB,
    ushort_t* __restrict__ WqT, ushort_t* __restrict__ WkvT)
{
  __shared__ float Ls[32][33];
  const int tid = threadIdx.x;
  int blk = (int)blockIdx.x;
  if (blk < 8192) { conv_body(tokens, Tok, blk, tid); return; }
  blk -= 8192;
  if (blk < 1536) { conv_body(context, CtxB, blk, tid); return; }
  blk -= 1536;
  if (blk < 1024) { convT_body(Wq, WqT, 1024, blk, tid, Ls); return; }
  blk -= 1024;
  if (blk < 768)  { convT_body(Wk, WkvT, 768, blk, tid, Ls); return; }
  blk -= 768;
  convT_body(Wv, WkvT + (size_t)1024 * 768, 768, blk, tid, Ls);
}

__global__ __launch_bounds__(256) void prepO(const float* __restrict__ Wo,
                                             ushort_t* __restrict__ WoT) {
  __shared__ float Ls[32][33];
  convT_body(Wo, WoT, 1024, (int)blockIdx.x, threadIdx.x, Ls);
}

// ---- gemm128kv: C = CtxB[4096][768] @ WkvT[2048][768]^T, dual epilogue ----
// cols [0,1024): K bf16 row-major [B*S][EMB]; cols [1024,2048): V^T [B][H][D][S]
__global__ __launch_bounds__(256) void gemm128kv(
    const ushort_t* __restrict__ A, const ushort_t* __restrict__ Bt,
    ushort_t* __restrict__ Kb, ushort_t* __restrict__ Vtb)
{
  __shared__ ushort_t As[128 * 32];
  __shared__ ushort_t Bs[128 * 32];
  const int Kd = CTX_;
  const int tid = threadIdx.x;
  const int bn = blockIdx.x, bm = blockIdx.y;
  const int lane = tid & 63, w = tid >> 6;
  const int lr = lane & 15, lg = lane >> 4;
  const int wr = w >> 1, wc = w & 1;

  f32x4 acc[4][4] = {};

  const int srow = tid >> 2, scol = (tid & 3) * 8;
  const ushort_t* ga = A + (size_t)(bm * 128 + srow) * Kd + scol;
  const ushort_t* gb = Bt + (size_t)(bn * 128 + srow) * Kd + scol;
  ushort_t* la = &As[tid * 8];
  ushort_t* lb = &Bs[tid * 8];
  const size_t rstep = (size_t)64 * Kd;

  for (int k0 = 0; k0 < Kd; k0 += 32) {
    gload16(ga + k0, la);
    gload16(ga + k0 + rstep, la + 2048);
    gload16(gb + k0, lb);
    gload16(gb + k0 + rstep, lb + 2048);
    __syncthreads();
    short8 af[4], bf[4];
#pragma unroll
    for (int m = 0; m < 4; ++m)
      af[m] = *(const short8*)&As[(wr * 64 + m * 16 + lr) * 32 + lg * 8];
#pragma unroll
    for (int n = 0; n < 4; ++n)
      bf[n] = *(const short8*)&Bs[(wc * 64 + n * 16 + lr) * 32 + lg * 8];
#pragma unroll
    for (int m = 0; m < 4; ++m)
#pragma unroll
      for (int n = 0; n < 4; ++n)
        acc[m][n] = __builtin_amdgcn_mfma_f32_16x16x32_bf16(af[m], bf[n], acc[m][n], 0, 0, 0);
    __syncthreads();
  }

  const int row0 = bm * 128 + wr * 64 + lg * 4;
  const int col0 = bn * 128 + wc * 64 + lr;

  if (col0 < 1024) {       // K half (per-wave uniform: 64-col span)
#pragma unroll
    for (int m = 0; m < 4; ++m)
#pragma unroll
      for (int n = 0; n < 4; ++n) {
        const int col = col0 + n * 16;
#pragma unroll
        for (int i = 0; i < 4; ++i)
          Kb[(size_t)(row0 + m * 16 + i) * EMB_ + col] = f2b_fast(acc[m][n][i]);
      }
  } else {                 // V half -> V^T [B][H][D][S]
#pragma unroll
    for (int m = 0; m < 4; ++m) {
      const int rbase = row0 + m * 16;
      const int bb = rbase >> 10;
      const int s0 = rbase & (S_ - 1);
#pragma unroll
      for (int n = 0; n < 4; ++n) {
        const int vc = col0 + n * 16 - 1024;
        const int hh = vc >> 6, dd = vc & 63;
        us4 o;
        o.x = f2b_fast(acc[m][n][0]); o.y = f2b_fast(acc[m][n][1]);
        o.z = f2b_fast(acc[m][n][2]); o.w = f2b_fast(acc[m][n][3]);
        *(us4*)&Vtb[(((size_t)bb * H_ + hh) * D_ + dd) * S_ + s0] = o;
      }
    }
  }
}

// ---- gemm256: 256x256 tile, 8 waves (2Mx4N), counted-vmcnt 4-slot ring ----
// EPI: 1 = bf16 out * QSCALE, 3 = f32 + bias
template<int EPI>
__global__ __launch_bounds__(512) void gemm256(
    const ushort_t* __restrict__ A, const ushort_t* __restrict__ Bt,
    void* __restrict__ Cp, const float* __restrict__ bias,
    int M, int Kd, int N)
{
  extern __shared__ ushort_t L[];
  const int tid = threadIdx.x;
  const int lane = tid & 63, wid = tid >> 6;
  const int lr = lane & 15, lg = lane >> 4;
  const int wm = wid >> 2, wn = wid & 3;

  const int cpx = (int)gridDim.x >> 3;
  const int lin = (int)blockIdx.x;
  const int swz = (lin & 7) * cpx + (lin >> 3);
  const int nbn = N >> 8;
  const int bm = swz / nbn, bn = swz % nbn;

  const int sr = tid >> 2;
  const int csrc = (tid & 3) ^ ((sr >> 1) & 3);
  const ushort_t* gA = A + (size_t)(bm * 256 + sr) * Kd + csrc * 8;
  const ushort_t* gB = Bt + (size_t)(bn * 256 + sr) * Kd + csrc * 8;
  const size_t half = (size_t)128 * Kd;
  ushort_t* const dA = L + tid * 8;
  ushort_t* const dB = L + 8192 + tid * 8;

  f32x4 acc[8][4] = {};
  const int NT = Kd >> 5;

#define STAGE256(c) do {                                \
    const int slot_ = ((c) & 3) * 16384;                \
    const int k0_ = (c) << 5;                           \
    gload16(gA + k0_, dA + slot_);                      \
    gload16(gA + k0_ + half, dA + slot_ + 4096);        \
    gload16(gB + k0_, dB + slot_);                      \
    gload16(gB + k0_ + half, dB + slot_ + 4096);        \
  } while (0)

  STAGE256(0); STAGE256(1); STAGE256(2);
  asm volatile("s_waitcnt vmcnt(8)" ::: "memory");
  __builtin_amdgcn_s_barrier();
  __builtin_amdgcn_sched_barrier(0);

  for (int t = 0; t < NT; ++t) {
    if (t + 3 < NT) STAGE256(t + 3);
    const ushort_t* As_ = L + (t & 3) * 16384;
    const ushort_t* Bs_ = As_ + 8192;
    short8 af[8], bf[4];
#pragma unroll
    for (int m = 0; m < 8; ++m) {
      const int row = wm * 128 + m * 16 + lr;
      af[m] = *(const short8*)&As_[row * 32 + (lg ^ ((row >> 1) & 3)) * 8];
    }
#pragma unroll
    for (int n = 0; n < 4; ++n) {
      const int row = wn * 64 + n * 16 + lr;
      bf[n] = *(const short8*)&Bs_[row * 32 + (lg ^ ((row >> 1) & 3)) * 8];
    }
    __builtin_amdgcn_s_setprio(1);
#pragma unroll
    for (int m = 0; m < 8; ++m)
#pragma unroll
      for (int n = 0; n < 4; ++n)
        acc[m][n] = __builtin_amdgcn_mfma_f32_16x16x32_bf16(af[m], bf[n], acc[m][n], 0, 0, 0);
    __builtin_amdgcn_s_setprio(0);
    asm volatile("s_waitcnt vmcnt(8)" ::: "memory");
    __builtin_amdgcn_s_barrier();
    __builtin_amdgcn_sched_barrier(0);
  }
#undef STAGE256

  const int row0 = bm * 256 + wm * 128 + lg * 4;
  const int col0 = bn * 256 + wn * 64 + lr;

  if constexpr (EPI == 3) {
    float* C = (float*)Cp;
#pragma unroll
    for (int n = 0; n < 4; ++n) {
      const int col = col0 + n * 16;
      const float bv = bias[col];
#pragma unroll
      for (int m = 0; m < 8; ++m)
#pragma unroll
        for (int i = 0; i < 4; ++i)
          C[(size_t)(row0 + m * 16 + i) * N + col] = acc[m][n][i] + bv;
    }
  } else {
    ushort_t* C = (ushort_t*)Cp;
#pragma unroll
    for (int m = 0; m < 8; ++m)
#pragma unroll
      for (int n = 0; n < 4; ++n) {
        const int col = col0 + n * 16;
#pragma unroll
        for (int i = 0; i < 4; ++i)
          C[(size_t)(row0 + m * 16 + i) * N + col] = f2b(acc[m][n][i] * QSCALE);
      }
  }
}

// ---- flash attention v5r: QBLK=256 (8 waves x 32 rows), SBLK=64, swapped QK^T,
//      no-max exp2 softmax, l via ones-MFMA, double-buffered K/V prefetch,
//      1D grid with same-(b,h)->same-XCD bijective swizzle ----
__global__ __launch_bounds__(512) void attn_v5r(
    const ushort_t* __restrict__ Q, const ushort_t* __restrict__ K,
    const ushort_t* __restrict__ Vt, ushort_t* __restrict__ C)
{
  __shared__ ushort_t Ks[2][64 * 64];
  __shared__ ushort_t Vs[2][64 * 64];
  __shared__ ushort_t Ps[8][16][72];
  const int tid = threadIdx.x;
  const int lane = tid & 63, w = tid >> 6;
  const int lr = lane & 15, lg = lane >> 4;

  // bijective decode: all 16 t-blocks of one (b,h) share dispatch-id mod 8
  const int bid = (int)blockIdx.x;
  const int g = (bid & 7) | (((bid >> 3) >> 4) << 3);   // (b,h) group 0..63
  const int tb = (bid >> 3) & 15;                        // t-chunk 0..15
  const int h = g & 15, b = g >> 4;
  const int t0 = tb * 256;

  short8 qf[2][2];
#pragma unroll
  for (int qs = 0; qs < 2; ++qs) {
    const size_t qrow = (size_t)b * T_ + t0 + w * 32 + qs * 16 + lr;
    const ushort_t* qp = Q + qrow * EMB_ + h * 64;
    qf[qs][0] = *(const short8*)(qp + lg * 8);
    qf[qs][1] = *(const short8*)(qp + 32 + lg * 8);
  }

  short8 ones;
#pragma unroll
  for (int j = 0; j < 8; ++j) ones[j] = (short)0x3F80;

  f32x4 o[2][4] = {};
  f32x4 lacc[2] = {};

  const int srow = tid >> 3, schunk = tid & 7;
  const int sswz = schunk ^ (srow & 7);
  const ushort_t* kg = K + ((size_t)b * S_ + srow) * EMB_ + h * 64 + sswz * 8;
  const ushort_t* vg = Vt + (((size_t)b * H_ + h) * D_ + srow) * S_ + sswz * 8;

  gload16(kg, &Ks[0][tid * 8]);
  gload16(vg, &Vs[0][tid * 8]);

  int cur = 0;
  for (int st = 0; st < S_ / 64; ++st) {
    __syncthreads();   // vmcnt(0)+barrier: tile st landed; buf[cur^1] reads closed
    if (st + 1 < S_ / 64) {
      gload16(kg + (size_t)(st + 1) * 64 * EMB_, &Ks[cur ^ 1][tid * 8]);
      gload16(vg + (st + 1) * 64, &Vs[cur ^ 1][tid * 8]);
    }

    f32x4 sacc[2][4] = {};
    __builtin_amdgcn_s_setprio(1);
#pragma unroll
    for (int c = 0; c < 4; ++c) {
      const int krow = c * 16 + lr;
      const int sw = krow & 7;
      const short8 ka0 = *(const short8*)&Ks[cur][krow * 64 + ((lg ^ sw) * 8)];
      const short8 ka1 = *(const short8*)&Ks[cur][krow * 64 + (((4 + lg) ^ sw) * 8)];
#pragma unroll
      for (int qs = 0; qs < 2; ++qs) {
        sacc[qs][c] = __builtin_amdgcn_mfma_f32_16x16x32_bf16(ka0, qf[qs][0], sacc[qs][c], 0, 0, 0);
        sacc[qs][c] = __builtin_amdgcn_mfma_f32_16x16x32_bf16(ka1, qf[qs][1], sacc[qs][c], 0, 0, 0);
      }
    }
    __builtin_amdgcn_s_setprio(0);

    short8 pa[2][2];
#pragma unroll
    for (int qs = 0; qs < 2; ++qs) {
#pragma unroll
      for (int c = 0; c < 4; ++c) {
        uint2 pk;
        pk.x = cvtpk2(exp2f(sacc[qs][c][0]), exp2f(sacc[qs][c][1]));
        pk.y = cvtpk2(exp2f(sacc[qs][c][2]), exp2f(sacc[qs][c][3]));
        *(uint2*)&Ps[w][lr][c * 16 + lg * 4] = pk;
      }
      pa[qs][0] = *(const short8*)&Ps[w][lr][lg * 8];
      pa[qs][1] = *(const short8*)&Ps[w][lr][32 + lg * 8];
    }

    __builtin_amdgcn_s_setprio(1);
#pragma unroll
    for (int sh = 0; sh < 2; ++sh) {
#pragma unroll
      for (int dc = 0; dc < 4; ++dc) {
        const int vrow = dc * 16 + lr;
        const int vsw = vrow & 7;
        const short8 vb = *(const short8*)&Vs[cur][vrow * 64 + (((sh * 4 + lg) ^ vsw) * 8)];
        o[0][dc] = __builtin_amdgcn_mfma_f32_16x16x32_bf16(pa[0][sh], vb, o[0][dc], 0, 0, 0);
        o[1][dc] = __builtin_amdgcn_mfma_f32_16x16x32_bf16(pa[1][sh], vb, o[1][dc], 0, 0, 0);
      }
      lacc[0] = __builtin_amdgcn_mfma_f32_16x16x32_bf16(pa[0][sh], ones, lacc[0], 0, 0, 0);
      lacc[1] = __builtin_amdgcn_mfma_f32_16x16x32_bf16(pa[1][sh], ones, lacc[1], 0, 0, 0);
    }
    __builtin_amdgcn_s_setprio(0);

    cur ^= 1;
  }

#pragma unroll
  for (int qs = 0; qs < 2; ++qs) {
#pragma unroll
    for (int i = 0; i < 4; ++i) {
      const float li = 1.0f / lacc[qs][i];
      const size_t trow = (size_t)b * T_ + t0 + w * 32 + qs * 16 + lg * 4 + i;
#pragma unroll
      for (int dc = 0; dc < 4; ++dc)
        C[trow * EMB_ + h * 64 + dc * 16 + lr] = f2b_fast(o[qs][dc][i] * li);
    }
  }
}

extern "C" void kernel_launch(void* const* d_in, const int* in_sizes, int n_in,
                              void* d_out, int out_size, void* d_ws, size_t ws_size,
                              hipStream_t stream) {
  const float* tokens  = (const float*)d_in[0];
  const float* context = (const float*)d_in[1];
  const float* Wq = (const float*)d_in[2];
  const float* Wk = (const float*)d_in[3];
  const float* Wv = (const float*)d_in[4];
  const float* Wo = (const float*)d_in[5];
  const float* bo = (const float*)d_in[6];
  float* out = (float*)d_out;

  // d_out doubles as scratch until the final O-proj overwrites it:
  ushort_t* Qb  = (ushort_t*)d_out;                      // 16.78M ushorts
  ushort_t* Tok = Qb + (size_t)B_ * T_ * EMB_;           // 16.78M ushorts
  // ws: Kb(8.4M B) | Vtb(8.4) | Cb(33.6, ctx bf16 then attn out) | WqT(2)/WoT | WkvT(3.1)
  ushort_t* Kb   = (ushort_t*)d_ws;
  ushort_t* Vtb  = Kb + (size_t)B_ * S_ * EMB_;
  ushort_t* Cb   = Vtb + (size_t)B_ * S_ * EMB_;
  ushort_t* WqT  = Cb + (size_t)B_ * T_ * EMB_;
  ushort_t* WkvT = WqT + (size_t)EMB_ * HID_;

  // 1. fused prep: tokens->bf16, context->bf16, Wq^T, Wk^T, Wv^T
  prepA<<<12288, 256, 0, stream>>>(tokens, context, Wq, Wk, Wv,
                                   Tok, Cb, WqT, WkvT);
  // 2. Q-proj (QSCALE in epilogue)
  gemm256<1><<<dim3((B_ * T_ / 256) * (EMB_ / 256)), 512, 131072, stream>>>(
      Tok, WqT, Qb, nullptr, B_ * T_, HID_, EMB_);
  // 3. Wo^T (reuses WqT slot — Q-proj is done with it)
  prepO<<<1024, 256, 0, stream>>>(Wo, WqT);
  // 4. fused K+V proj, dual epilogue
  gemm128kv<<<dim3(16, 32), 256, 0, stream>>>(Cb, WkvT, Kb, Vtb);
  // 5. attention -> ctx bf16 (overwrites Cb)
  attn_v5r<<<dim3((T_ / 256) * H_ * B_), 512, 0, stream>>>(Qb, Kb, Vtb, Cb);
  // 6. O-proj + bias -> f32 out
  gemm256<3><<<dim3((B_ * T_ / 256) * (HID_ / 256)), 512, 131072, stream>>>(
      Cb, WqT, out, bo, B_ * T_, EMB_, HID_);
}